// Round 9
// baseline (165.152 us; speedup 1.0000x reference)
//
#include <hip/hip_runtime.h>
#include <hip/hip_bf16.h>
#include <stdint.h>

#define SEQ 2048
#define HID 2048
#define NH 16
#define HD 128
// 1/sqrt(128) * log2(e): softmax runs in exp2 domain
#define QSCALE_L2E 0.1275304429019769f

typedef __attribute__((ext_vector_type(4))) float f32x4;
typedef __attribute__((ext_vector_type(8))) short short8;
typedef __attribute__((ext_vector_type(4))) float f4;
typedef __attribute__((ext_vector_type(4))) int i32x4;
typedef __attribute__((ext_vector_type(4))) unsigned short us4;

__device__ __forceinline__ unsigned short f2bu(float f) {
  union { float f; unsigned int u; } c; c.f = f;
  unsigned int u = c.u + 0x7fffu + ((c.u >> 16) & 1u);  // RNE, finite inputs
  return (unsigned short)(u >> 16);
}

__device__ __forceinline__ unsigned short f2bu_fast(float f) {
  union { float f; unsigned int u; } c; c.f = f;
  return (unsigned short)((c.u + 0x8000u) >> 16);
}

__device__ __forceinline__ float b2f(unsigned short u) {
  union { unsigned int u; float f; } c; c.u = ((unsigned int)u) << 16; return c.f;
}

__device__ __forceinline__ float exp2fast(float x) {
  float r; asm("v_exp_f32 %0, %1" : "=v"(r) : "v"(x)); return r;
}

__device__ __forceinline__ void gload_lds16(const void* g, void* l) {
  __builtin_amdgcn_global_load_lds((const __attribute__((address_space(1))) void*)g,
                                   (__attribute__((address_space(3))) void*)l, 16, 0, 0);
}

#define BAR() __builtin_amdgcn_s_barrier()
#define LGKM0() do { asm volatile("s_waitcnt lgkmcnt(0)" ::: "memory"); __builtin_amdgcn_sched_barrier(0); } while (0)
#define VM6()   do { asm volatile("s_waitcnt vmcnt(6)"   ::: "memory"); __builtin_amdgcn_sched_barrier(0); } while (0)
#define VM0()   do { asm volatile("s_waitcnt vmcnt(0)"   ::: "memory"); __builtin_amdgcn_sched_barrier(0); } while (0)

// ---------------- fp32 -> bf16 convert, 5 equal-size arrays (32B/thread) ----
__global__ __launch_bounds__(256) void cvt_kernel(
    const float* __restrict__ s0, const float* __restrict__ s1,
    const float* __restrict__ s2, const float* __restrict__ s3,
    const float* __restrict__ s4,
    unsigned short* __restrict__ d0, unsigned short* __restrict__ d1,
    unsigned short* __restrict__ d2, unsigned short* __restrict__ d3,
    unsigned short* __restrict__ d4, int n)
{
  const float* s; unsigned short* d;
  switch (blockIdx.y) {
    case 0: s = s0; d = d0; break;
    case 1: s = s1; d = d1; break;
    case 2: s = s2; d = d2; break;
    case 3: s = s3; d = d3; break;
    default: s = s4; d = d4; break;
  }
  const int stride = gridDim.x * blockDim.x;
  for (int i = blockIdx.x * blockDim.x + threadIdx.x; i * 8 < n; i += stride) {
    f4 v0 = *(const f4*)&s[i * 8];
    f4 v1 = *(const f4*)&s[i * 8 + 4];
    short8 o;
    o[0] = (short)f2bu(v0[0]); o[1] = (short)f2bu(v0[1]);
    o[2] = (short)f2bu(v0[2]); o[3] = (short)f2bu(v0[3]);
    o[4] = (short)f2bu(v1[0]); o[5] = (short)f2bu(v1[1]);
    o[6] = (short)f2bu(v1[2]); o[7] = (short)f2bu(v1[3]);
    *(short8*)&d[i * 8] = o;
  }
}

// ---------------- 128x128 bf16 GEMM, m97-style single-buffer ----------------
// R18-verified WIN (QKV 77 -> ~50us): BM=BN=128, BK=64, 4 waves (2Mx2N),
// per-wave 64x64 (acc[4][4]). SINGLE 32KB LDS buffer + launch_bounds(256,3)
// -> 3 blocks/CU; the per-tile vmcnt(0)+barrier drain is covered by the
// OTHER resident blocks (m114 cross-block MFMA/staging overlap).
template<int MODE>
__global__ __launch_bounds__(256, 3) void gemm97(
    const unsigned short* __restrict__ A,
    const unsigned short* __restrict__ B,
    const float* __restrict__ b0, const float* __restrict__ b1, const float* __restrict__ b2,
    unsigned short* __restrict__ O0, unsigned short* __restrict__ O1, unsigned short* __restrict__ O2,
    float* __restrict__ Of, int M, int N, int K)
{
  extern __shared__ unsigned short lds[];  // A[128*64] @0, B[128*64] @8192 el
  const int tid = threadIdx.x;
  const int lane = tid & 63, w = tid >> 6;
  const int g = lane >> 4, q = lane & 15;
  const int wgM = w >> 1, wgN = w & 1;     // 2M x 2N wave grid
  const long bm = (long)blockIdx.y * 128, bn = (long)blockIdx.x * 128;
  const int NK = K >> 6;

  // staging lane geometry (proven): lane writes LDS row (l>>3), 16B-block
  // (l&7); global column block pre-swizzled: (l&7)^(l>>3)
  const int srl = lane >> 3;
  const int scE = ((lane & 7) ^ srl) * 8;
  // fragment read swizzle: logical k-block g of row r stored at g^(r&7);
  // all frag rows have row&7 == q&7
  const int c0 = (g ^ (q & 7)) * 8;
  const int c1 = c0 ^ 32;
  const int aB = (wgM * 64 + q) * 64;
  const int bB = (wgN * 64 + q) * 64;

  f32x4 acc[4][4] = {};
  short8 a[4][2], b[4][2];

#define STAGE(gp, gbase, jj, ldsOff) do {                                     \
    _Pragma("unroll")                                                         \
    for (int c_ = 0; c_ < 4; ++c_) {                                          \
      const long row_ = (c_ * 4 + w) * 8 + srl;                               \
      gload_lds16(&(gp)[((gbase) + row_) * (long)K + (jj) * 64 + scE],        \
                  &lds[(ldsOff) + (c_ * 4 + w) * 512]);                       \
    }                                                                         \
  } while (0)

#define QUADD(n0, n1)                                                         \
  do {                                                                        \
    __builtin_amdgcn_s_setprio(1);                                            \
    _Pragma("unroll")                                                         \
    for (int mi_ = 0; mi_ < 4; ++mi_) {                                       \
      acc[mi_][n0] = __builtin_amdgcn_mfma_f32_16x16x32_bf16(                 \
          a[mi_][0], b[n0][0], acc[mi_][n0], 0, 0, 0);                        \
      acc[mi_][n0] = __builtin_amdgcn_mfma_f32_16x16x32_bf16(                 \
          a[mi_][1], b[n0][1], acc[mi_][n0], 0, 0, 0);                        \
      acc[mi_][n1] = __builtin_amdgcn_mfma_f32_16x16x32_bf16(                 \
          a[mi_][0], b[n1][0], acc[mi_][n1], 0, 0, 0);                        \
      acc[mi_][n1] = __builtin_amdgcn_mfma_f32_16x16x32_bf16(                 \
          a[mi_][1], b[n1][1], acc[mi_][n1], 0, 0, 0);                        \
    }                                                                         \
    __builtin_amdgcn_s_setprio(0);                                            \
  } while (0)

  for (int j = 0; j < NK; ++j) {
    STAGE(A, bm, j, 0);
    STAGE(B, bn, j, 8192);
    VM0();                                  // tile landed
    BAR();                                  // all waves see full tile
#pragma unroll
    for (int mi = 0; mi < 4; ++mi) {
      a[mi][0] = *(const short8*)&lds[aB + mi * 1024 + c0];
      a[mi][1] = *(const short8*)&lds[aB + mi * 1024 + c1];
    }
#pragma unroll
    for (int ni = 0; ni < 4; ++ni) {
      b[ni][0] = *(const short8*)&lds[8192 + bB + ni * 1024 + c0];
      b[ni][1] = *(const short8*)&lds[8192 + bB + ni * 1024 + c1];
    }
    QUADD(0, 1);
    QUADD(2, 3);
    BAR();                                  // all reads done -> safe to restage
  }

#pragma unroll
  for (int ni = 0; ni < 4; ++ni) {
    const int col = (int)bn + wgN * 64 + ni * 16 + q;
    float bv;
    if (MODE == 4) {
      const int which = col >> 11, c = col & 2047;
      const float* bp = which == 0 ? b0 : (which == 1 ? b1 : b2);
      bv = bp[c];
    } else {
      bv = b0[col];
    }
#pragma unroll
    for (int mi = 0; mi < 4; ++mi)
#pragma unroll
      for (int r = 0; r < 4; ++r) {
        const long row = bm + wgM * 64 + mi * 16 + 4 * g + r;
        const float v = acc[mi][ni][r] + bv;
        if (MODE == 4) {
          const int which = col >> 11, c = col & 2047, head = c >> 7, d = c & 127;
          if (which == 0)      O0[((long)head * SEQ + row) * HD + d] = f2bu(v * QSCALE_L2E);
          else if (which == 1) O1[((long)head * SEQ + row) * HD + d] = f2bu(v);
          else                 O2[((long)head * HD + d) * SEQ + row] = f2bu(v);
        } else {
          Of[row * (long)N + col] = v;
        }
      }
  }
#undef STAGE
#undef QUADD
}

// ---------------- 64x128 bf16 GEMM  C = A[M,K] * B[N,K]^T + bias ------------
// Kept for out-projection (grid 16x32 = 512 blocks; the 128^2 kernel would be
// 256 blocks = 1 block/CU -> no cross-block overlap).
template<int MODE>
__global__ __launch_bounds__(256, 2) void gemm128(
    const unsigned short* __restrict__ A,
    const unsigned short* __restrict__ B,
    const float* __restrict__ b0, const float* __restrict__ b1, const float* __restrict__ b2,
    unsigned short* __restrict__ O0, unsigned short* __restrict__ O1, unsigned short* __restrict__ O2,
    float* __restrict__ Of, int M, int N, int K)
{
  constexpr int ASZ = 64 * 64;
  constexpr int BSZ = 128 * 64;

  extern __shared__ unsigned short lds[];
  const int tid = threadIdx.x;
  const int lane = tid & 63, w = tid >> 6;
  const int g = lane >> 4, q = lane & 15;
  const long bm = (long)blockIdx.y * 64, bn = (long)blockIdx.x * 128;
  const int NK = K >> 6;

  const int srl = lane >> 3;
  const int scE = ((lane & 7) ^ srl) * 8;
  const int c0 = (g ^ (q & 7)) * 8;
  const int c1 = c0 ^ 32;
  const int aB = q * 64;
  const int bB = (w * 32 + q) * 64;

  f32x4 acc[4][2] = {};
  short8 a[4][2], b[2][2];

#define STAGE_A(jj) do {                                                      \
    unsigned short* dst_ = lds + (((jj) & 1) ? ASZ : 0);                      \
    _Pragma("unroll")                                                         \
    for (int c_ = 0; c_ < 2; ++c_) {                                          \
      const long row_ = (c_ * 4 + w) * 8 + srl;                               \
      gload_lds16(&A[(bm + row_) * (long)K + (jj) * 64 + scE],                \
                  &dst_[(c_ * 4 + w) * 512]);                                 \
    }                                                                         \
  } while (0)

#define STAGE_B(jj) do {                                                      \
    unsigned short* dst_ = lds + 2 * ASZ + (((jj) & 1) ? BSZ : 0);            \
    _Pragma("unroll")                                                         \
    for (int c_ = 0; c_ < 4; ++c_) {                                          \
      const long row_ = (c_ * 4 + w) * 8 + srl;                               \
      gload_lds16(&B[(bn + row_) * (long)K + (jj) * 64 + scE],                \
                  &dst_[(c_ * 4 + w) * 512]);                                 \
    }                                                                         \
  } while (0)

#define QUAD8(ni)                                                             \
  do {                                                                        \
    __builtin_amdgcn_s_setprio(1);                                            \
    _Pragma("unroll")                                                         \
    for (int mi_ = 0; mi_ < 4; ++mi_) {                                       \
      acc[mi_][ni] = __builtin_amdgcn_mfma_f32_16x16x32_bf16(                 \
          a[mi_][0], b[ni][0], acc[mi_][ni], 0, 0, 0);                        \
      acc[mi_][ni] = __builtin_amdgcn_mfma_f32_16x16x32_bf16(                 \
          a[mi_][1], b[ni][1], acc[mi_][ni], 0, 0, 0);                        \
    }                                                                         \
    __builtin_amdgcn_s_setprio(0);                                            \
  } while (0)

  STAGE_A(0); STAGE_B(0);
  STAGE_A(1); STAGE_B(1);
  VM6();
  BAR();

  for (int j = 0; j < NK; ++j) {
    unsigned short* At = lds + ((j & 1) ? ASZ : 0);
    unsigned short* Bt = lds + 2 * ASZ + ((j & 1) ? BSZ : 0);

#pragma unroll
    for (int mi = 0; mi < 4; ++mi) {
      a[mi][0] = *(const short8*)&At[aB + mi * 1024 + c0];
      a[mi][1] = *(const short8*)&At[aB + mi * 1024 + c1];
    }
#pragma unroll
    for (int ni = 0; ni < 2; ++ni) {
      b[ni][0] = *(const short8*)&Bt[bB + ni * 1024 + c0];
      b[ni][1] = *(const short8*)&Bt[bB + ni * 1024 + c1];
    }
    QUAD8(0);
    LGKM0();
    BAR();                                  // (a)
    if (j + 2 < NK) { STAGE_A(j + 2); STAGE_B(j + 2); }
    QUAD8(1);
    if (j < NK - 2) { VM6(); } else { VM0(); }
    BAR();                                  // (b)
  }

#pragma unroll
  for (int ni = 0; ni < 2; ++ni) {
    const int col = (int)bn + w * 32 + ni * 16 + q;
    float bv;
    if (MODE == 4) {
      const int which = col >> 11, c = col & 2047;
      const float* bp = which == 0 ? b0 : (which == 1 ? b1 : b2);
      bv = bp[c];
    } else {
      bv = b0[col];
    }
#pragma unroll
    for (int mi = 0; mi < 4; ++mi)
#pragma unroll
      for (int r = 0; r < 4; ++r) {
        const long row = bm + mi * 16 + 4 * g + r;
        const float v = acc[mi][ni][r] + bv;
        if (MODE == 4) {
          const int which = col >> 11, c = col & 2047, head = c >> 7, d = c & 127;
          if (which == 0)      O0[((long)head * SEQ + row) * HD + d] = f2bu(v * QSCALE_L2E);
          else if (which == 1) O1[((long)head * SEQ + row) * HD + d] = f2bu(v);
          else                 O2[((long)head * HD + d) * SEQ + row] = f2bu(v);
        } else {
          Of[row * (long)N + col] = v;
        }
      }
  }
#undef STAGE_A
#undef STAGE_B
#undef QUAD8
}

// ---------------- flash attention v11: swapped QK^T + shfl P-exchange -------
// R23: kills the Pt LDS round-trip (16 scalar conflicted ds_writes/tile =
// 4.19M conflict cycles). (1) QK^T operands SWAPPED -> lane (q,g) holds
// P[Qrow=q][Krow=kc*16+4g+r]: Q-row is lane-local. (2) P -> PV-A fragment
// rebuilt in-register: pack bf16 pairs W[kc][jp], then per (ks,m):
//   pf[ks].word[m] = W[2ks+(g>>1)][m&1] from lane q+32(g&1)+16(m>>1)
// (two shfls + select; verified element-wise vs the proven Pt read).
// lsum: per-lane row-q accumulator; end reduce shfl_xor(16/32); redistribute
// to (4g+r)-rows via 4 shfls. Pt gone -> 32KB static LDS.
#define KVB 64
__global__ __launch_bounds__(256) void flash_attn(
    const unsigned short* __restrict__ Qb,
    const unsigned short* __restrict__ Kb,
    const unsigned short* __restrict__ VTb,
    unsigned short* __restrict__ attnb)      // [SEQ][HID] bf16
{
  __shared__ __align__(16) unsigned short Kt[64 * 128];
  __shared__ __align__(16) unsigned short Vt[128 * 64];
  const int tid = threadIdx.x;
  const int l = tid & 63, w = tid >> 6;
  const int g = l >> 4, q = l & 15;
  const int bid = blockIdx.x;
  const int jj = bid >> 3;
  const int h = ((bid & 7) << 1) | (jj >> 5);   // 2 heads per XCD (R19-proven)
  const int qb = jj & 31;
  const int qrow0 = qb * 64 + w * 16;

  // shfl source lanes for the P exchange (hoisted)
  const int sl0 = q + ((g & 1) << 5);           // g_src = 2*(g&1)
  const int sl1 = sl0 + 16;                     // g_src = 2*(g&1)+1

  short8 qf[4];
#pragma unroll
  for (int dc = 0; dc < 4; ++dc)
    qf[dc] = *(const short8*)&Qb[((long)h * SEQ + qrow0 + q) * HD + dc * 32 + g * 8];

  f32x4 oacc[8] = {};
  float lsumL = 0.f;

  const int kr = tid >> 4, kc16 = tid & 15;
  const int vr = tid >> 3, vc8 = tid & 7;
  const unsigned short* Kg = Kb + (long)h * SEQ * HD;
  const unsigned short* Vg = VTb + (long)h * HD * SEQ;

  short8 kreg[4], vreg[4];
#pragma unroll
  for (int it = 0; it < 4; ++it) {
    kreg[it] = *(const short8*)&Kg[(long)(kr + it * 16) * HD + kc16 * 8];
    vreg[it] = *(const short8*)&Vg[(long)(vr + it * 32) * SEQ + vc8 * 8];
  }

  for (int kb = 0; kb < SEQ; kb += KVB) {
    __syncthreads();
#pragma unroll
    for (int it = 0; it < 4; ++it) {
      const int krow = kr + it * 16;
      *(short8*)&Kt[((krow * 256 + kc16 * 16) ^ ((krow & 7) << 4)) >> 1] = kreg[it];
      const int vrow = vr + it * 32;
      *(short8*)&Vt[((vrow * 128 + vc8 * 16) ^ ((vrow & 7) << 4)) >> 1] = vreg[it];
    }
    __syncthreads();
    if (kb + KVB < SEQ) {
#pragma unroll
      for (int it = 0; it < 4; ++it) {
        kreg[it] = *(const short8*)&Kg[(long)(kb + KVB + kr + it * 16) * HD + kc16 * 8];
        vreg[it] = *(const short8*)&Vg[(long)(vr + it * 32) * SEQ + kb + KVB + vc8 * 8];
      }
    }

    // swapped QK^T: sacc[kc][r] = S[Qrow=q][Krow=kc*16+4g+r]
    f32x4 sacc[4] = {};
    __builtin_amdgcn_s_setprio(1);
#pragma unroll
    for (int kc = 0; kc < 4; ++kc) {
      const int krow = kc * 16 + q;
      const int sw = (krow & 7) << 4;
#pragma unroll
      for (int dc = 0; dc < 4; ++dc) {
        short8 kf = *(const short8*)&Kt[((krow * 256 + dc * 64 + g * 16) ^ sw) >> 1];
        sacc[kc] = __builtin_amdgcn_mfma_f32_16x16x32_bf16(kf, qf[dc], sacc[kc], 0, 0, 0);
      }
    }
    __builtin_amdgcn_s_setprio(0);

    float p[4][4];
#pragma unroll
    for (int kc = 0; kc < 4; ++kc)
#pragma unroll
      for (int r = 0; r < 4; ++r) p[kc][r] = exp2fast(sacc[kc][r]);
    lsumL += ((p[0][0] + p[0][1]) + (p[0][2] + p[0][3]))
           + ((p[1][0] + p[1][1]) + (p[1][2] + p[1][3]))
           + ((p[2][0] + p[2][1]) + (p[2][2] + p[2][3]))
           + ((p[3][0] + p[3][1]) + (p[3][2] + p[3][3]));

    // pack: W[kc][jp] = bf16(p[kc][2jp]) | bf16(p[kc][2jp+1])<<16
    unsigned W[4][2];
#pragma unroll
    for (int kc = 0; kc < 4; ++kc) {
      W[kc][0] = (unsigned)f2bu_fast(p[kc][0]) | ((unsigned)f2bu_fast(p[kc][1]) << 16);
      W[kc][1] = (unsigned)f2bu_fast(p[kc][2]) | ((unsigned)f2bu_fast(p[kc][3]) << 16);
    }

    // rebuild pf[ks] (A-fragment rows=q) via shfl: word m from lane sl(m>>1),
    // register W[2ks+(g>>1)][m&1]
    short8 pf[2];
#pragma unroll
    for (int ks = 0; ks < 2; ++ks) {
      union { i32x4 i; short8 s; } u;
#pragma unroll
      for (int m = 0; m < 4; ++m) {
        const int src = (m >> 1) ? sl1 : sl0;
        const int lo = __shfl((int)W[2 * ks][m & 1], src, 64);
        const int hi = __shfl((int)W[2 * ks + 1][m & 1], src, 64);
        u.i[m] = (g & 2) ? hi : lo;
      }
      pf[ks] = u.s;
    }

    const int psw = (q & 7) << 4;
    __builtin_amdgcn_s_setprio(1);
#pragma unroll
    for (int dt = 0; dt < 8; ++dt) {
      const int vrow = dt * 16 + q;
#pragma unroll
      for (int ks = 0; ks < 2; ++ks) {
        short8 vf = *(const short8*)&Vt[((vrow * 128 + ks * 64 + g * 16) ^ psw) >> 1];
        oacc[dt] = __builtin_amdgcn_mfma_f32_16x16x32_bf16(pf[ks], vf, oacc[dt], 0, 0, 0);
      }
    }
    __builtin_amdgcn_s_setprio(0);
  }

  // full row-sum for row q at every lane, then redistribute to rows 4g+r
  lsumL += __shfl_xor(lsumL, 16);
  lsumL += __shfl_xor(lsumL, 32);
  float rl[4];
#pragma unroll
  for (int r = 0; r < 4; ++r) rl[r] = 1.f / __shfl(lsumL, 4 * g + r, 64);

#pragma unroll
  for (int dt = 0; dt < 8; ++dt) {
    const long colb = (long)h * HD + dt * 16 + q;
#pragma unroll
    for (int r = 0; r < 4; ++r)
      attnb[(long)(qrow0 + 4 * g + r) * HID + colb] = f2bu(oacc[dt][r] * rl[r]);
  }
}

extern "C" void kernel_launch(void* const* d_in, const int* in_sizes, int n_in,
                              void* d_out, int out_size, void* d_ws, size_t ws_size,
                              hipStream_t stream)
{
  const float* x  = (const float*)d_in[0];
  const float* wq = (const float*)d_in[1];
  const float* bq = (const float*)d_in[2];
  const float* wk = (const float*)d_in[3];
  const float* bk = (const float*)d_in[4];
  const float* wv = (const float*)d_in[5];
  const float* bv = (const float*)d_in[6];
  const float* wo = (const float*)d_in[7];
  const float* bo = (const float*)d_in[8];

  const long NEL = (long)HID * HID;
  unsigned short* Xb   = (unsigned short*)d_ws;
  unsigned short* Wqkv = Xb + NEL;
  unsigned short* Wob  = Wqkv + 3 * NEL;
  unsigned short* Qbuf = Wob + NEL;
  unsigned short* Kbuf = Qbuf + NEL;
  unsigned short* VTb  = Kbuf + NEL;
  unsigned short* Attn = VTb + NEL;

  cvt_kernel<<<dim3(512, 5), 256, 0, stream>>>(
      x, wq, wk, wv, wo, Xb, Wqkv, Wqkv + NEL, Wqkv + 2 * NEL, Wob, (int)NEL);

  gemm97<4><<<dim3(48, 16), 256, 32768, stream>>>(
      Xb, Wqkv, bq, bk, bv, Qbuf, Kbuf, VTb, nullptr, SEQ, 3 * HID, HID);

  flash_attn<<<dim3(512), 256, 0, stream>>>(Qbuf, Kbuf, VTb, Attn);

  gemm128<3><<<dim3(16, 32), 256, 49152, stream>>>(
      Attn, Wob, bo, nullptr, nullptr, nullptr, nullptr, nullptr,
      (float*)d_out, SEQ, HID, HID);
}

// Round 10
// 163.997 us; speedup vs baseline: 1.0070x; 1.0070x over previous
//
#include <hip/hip_runtime.h>
#include <hip/hip_bf16.h>
#include <stdint.h>

#define SEQ 2048
#define HID 2048
#define NH 16
#define HD 128
// 1/sqrt(128) * log2(e): softmax runs in exp2 domain
#define QSCALE_L2E 0.1275304429019769f

typedef __attribute__((ext_vector_type(4))) float f32x4;
typedef __attribute__((ext_vector_type(8))) short short8;
typedef __attribute__((ext_vector_type(4))) float f4;
typedef __attribute__((ext_vector_type(4))) unsigned short us4;

__device__ __forceinline__ unsigned short f2bu(float f) {
  union { float f; unsigned int u; } c; c.f = f;
  unsigned int u = c.u + 0x7fffu + ((c.u >> 16) & 1u);  // RNE, finite inputs
  return (unsigned short)(u >> 16);
}

__device__ __forceinline__ unsigned short f2bu_fast(float f) {
  union { float f; unsigned int u; } c; c.f = f;
  return (unsigned short)((c.u + 0x8000u) >> 16);
}

__device__ __forceinline__ float b2f(unsigned short u) {
  union { unsigned int u; float f; } c; c.u = ((unsigned int)u) << 16; return c.f;
}

__device__ __forceinline__ float exp2fast(float x) {
  float r; asm("v_exp_f32 %0, %1" : "=v"(r) : "v"(x)); return r;
}

__device__ __forceinline__ void gload_lds16(const void* g, void* l) {
  __builtin_amdgcn_global_load_lds((const __attribute__((address_space(1))) void*)g,
                                   (__attribute__((address_space(3))) void*)l, 16, 0, 0);
}

#define BAR() __builtin_amdgcn_s_barrier()
#define LGKM0() do { asm volatile("s_waitcnt lgkmcnt(0)" ::: "memory"); __builtin_amdgcn_sched_barrier(0); } while (0)
#define VM6()   do { asm volatile("s_waitcnt vmcnt(6)"   ::: "memory"); __builtin_amdgcn_sched_barrier(0); } while (0)
#define VM8()   do { asm volatile("s_waitcnt vmcnt(8)"   ::: "memory"); __builtin_amdgcn_sched_barrier(0); } while (0)
#define VM0()   do { asm volatile("s_waitcnt vmcnt(0)"   ::: "memory"); __builtin_amdgcn_sched_barrier(0); } while (0)

// ---------------- fp32 -> bf16 convert, 5 equal-size arrays (32B/thread) ----
__global__ __launch_bounds__(256) void cvt_kernel(
    const float* __restrict__ s0, const float* __restrict__ s1,
    const float* __restrict__ s2, const float* __restrict__ s3,
    const float* __restrict__ s4,
    unsigned short* __restrict__ d0, unsigned short* __restrict__ d1,
    unsigned short* __restrict__ d2, unsigned short* __restrict__ d3,
    unsigned short* __restrict__ d4, int n)
{
  const float* s; unsigned short* d;
  switch (blockIdx.y) {
    case 0: s = s0; d = d0; break;
    case 1: s = s1; d = d1; break;
    case 2: s = s2; d = d2; break;
    case 3: s = s3; d = d3; break;
    default: s = s4; d = d4; break;
  }
  const int stride = gridDim.x * blockDim.x;
  for (int i = blockIdx.x * blockDim.x + threadIdx.x; i * 8 < n; i += stride) {
    f4 v0 = *(const f4*)&s[i * 8];
    f4 v1 = *(const f4*)&s[i * 8 + 4];
    short8 o;
    o[0] = (short)f2bu(v0[0]); o[1] = (short)f2bu(v0[1]);
    o[2] = (short)f2bu(v0[2]); o[3] = (short)f2bu(v0[3]);
    o[4] = (short)f2bu(v1[0]); o[5] = (short)f2bu(v1[1]);
    o[6] = (short)f2bu(v1[2]); o[7] = (short)f2bu(v1[3]);
    *(short8*)&d[i * 8] = o;
  }
}

// ---------------- 128x128 bf16 GEMM, m97-style single-buffer ----------------
// R18-verified WIN (QKV 77 -> ~50us): BM=BN=128, BK=64, 4 waves (2Mx2N),
// per-wave 64x64 (acc[4][4]). SINGLE 32KB LDS buffer + launch_bounds(256,3)
// -> 3 blocks/CU; the per-tile vmcnt(0)+barrier drain is covered by the
// OTHER resident blocks (m114 cross-block MFMA/staging overlap).
template<int MODE>
__global__ __launch_bounds__(256, 3) void gemm97(
    const unsigned short* __restrict__ A,
    const unsigned short* __restrict__ B,
    const float* __restrict__ b0, const float* __restrict__ b1, const float* __restrict__ b2,
    unsigned short* __restrict__ O0, unsigned short* __restrict__ O1, unsigned short* __restrict__ O2,
    float* __restrict__ Of, int M, int N, int K)
{
  extern __shared__ unsigned short lds[];  // A[128*64] @0, B[128*64] @8192 el
  const int tid = threadIdx.x;
  const int lane = tid & 63, w = tid >> 6;
  const int g = lane >> 4, q = lane & 15;
  const int wgM = w >> 1, wgN = w & 1;     // 2M x 2N wave grid
  const long bm = (long)blockIdx.y * 128, bn = (long)blockIdx.x * 128;
  const int NK = K >> 6;

  // staging lane geometry (proven): lane writes LDS row (l>>3), 16B-block
  // (l&7); global column block pre-swizzled: (l&7)^(l>>3)
  const int srl = lane >> 3;
  const int scE = ((lane & 7) ^ srl) * 8;
  // fragment read swizzle: logical k-block g of row r stored at g^(r&7);
  // all frag rows have row&7 == q&7
  const int c0 = (g ^ (q & 7)) * 8;
  const int c1 = c0 ^ 32;
  const int aB = (wgM * 64 + q) * 64;
  const int bB = (wgN * 64 + q) * 64;

  f32x4 acc[4][4] = {};
  short8 a[4][2], b[4][2];

#define STAGE(gp, gbase, jj, ldsOff) do {                                     \
    _Pragma("unroll")                                                         \
    for (int c_ = 0; c_ < 4; ++c_) {                                          \
      const long row_ = (c_ * 4 + w) * 8 + srl;                               \
      gload_lds16(&(gp)[((gbase) + row_) * (long)K + (jj) * 64 + scE],        \
                  &lds[(ldsOff) + (c_ * 4 + w) * 512]);                       \
    }                                                                         \
  } while (0)

#define QUADD(n0, n1)                                                         \
  do {                                                                        \
    __builtin_amdgcn_s_setprio(1);                                            \
    _Pragma("unroll")                                                         \
    for (int mi_ = 0; mi_ < 4; ++mi_) {                                       \
      acc[mi_][n0] = __builtin_amdgcn_mfma_f32_16x16x32_bf16(                 \
          a[mi_][0], b[n0][0], acc[mi_][n0], 0, 0, 0);                        \
      acc[mi_][n0] = __builtin_amdgcn_mfma_f32_16x16x32_bf16(                 \
          a[mi_][1], b[n0][1], acc[mi_][n0], 0, 0, 0);                        \
      acc[mi_][n1] = __builtin_amdgcn_mfma_f32_16x16x32_bf16(                 \
          a[mi_][0], b[n1][0], acc[mi_][n1], 0, 0, 0);                        \
      acc[mi_][n1] = __builtin_amdgcn_mfma_f32_16x16x32_bf16(                 \
          a[mi_][1], b[n1][1], acc[mi_][n1], 0, 0, 0);                        \
    }                                                                         \
    __builtin_amdgcn_s_setprio(0);                                            \
  } while (0)

  for (int j = 0; j < NK; ++j) {
    STAGE(A, bm, j, 0);
    STAGE(B, bn, j, 8192);
    VM0();                                  // tile landed
    BAR();                                  // all waves see full tile
#pragma unroll
    for (int mi = 0; mi < 4; ++mi) {
      a[mi][0] = *(const short8*)&lds[aB + mi * 1024 + c0];
      a[mi][1] = *(const short8*)&lds[aB + mi * 1024 + c1];
    }
#pragma unroll
    for (int ni = 0; ni < 4; ++ni) {
      b[ni][0] = *(const short8*)&lds[8192 + bB + ni * 1024 + c0];
      b[ni][1] = *(const short8*)&lds[8192 + bB + ni * 1024 + c1];
    }
    QUADD(0, 1);
    QUADD(2, 3);
    BAR();                                  // all reads done -> safe to restage
  }

#pragma unroll
  for (int ni = 0; ni < 4; ++ni) {
    const int col = (int)bn + wgN * 64 + ni * 16 + q;
    float bv;
    if (MODE == 4) {
      const int which = col >> 11, c = col & 2047;
      const float* bp = which == 0 ? b0 : (which == 1 ? b1 : b2);
      bv = bp[c];
    } else {
      bv = b0[col];
    }
#pragma unroll
    for (int mi = 0; mi < 4; ++mi)
#pragma unroll
      for (int r = 0; r < 4; ++r) {
        const long row = bm + wgM * 64 + mi * 16 + 4 * g + r;
        const float v = acc[mi][ni][r] + bv;
        if (MODE == 4) {
          const int which = col >> 11, c = col & 2047, head = c >> 7, d = c & 127;
          if (which == 0)      O0[((long)head * SEQ + row) * HD + d] = f2bu(v * QSCALE_L2E);
          else if (which == 1) O1[((long)head * SEQ + row) * HD + d] = f2bu(v);
          else                 O2[((long)head * HD + d) * SEQ + row] = f2bu(v);
        } else {
          Of[row * (long)N + col] = v;
        }
      }
  }
#undef STAGE
#undef QUADD
}

// ---------------- 64x128 bf16 GEMM  C = A[M,K] * B[N,K]^T + bias ------------
// Kept for out-projection (grid 16x32 = 512 blocks; the 128^2 kernel would be
// 256 blocks = 1 block/CU -> no cross-block overlap).
template<int MODE>
__global__ __launch_bounds__(256, 2) void gemm128(
    const unsigned short* __restrict__ A,
    const unsigned short* __restrict__ B,
    const float* __restrict__ b0, const float* __restrict__ b1, const float* __restrict__ b2,
    unsigned short* __restrict__ O0, unsigned short* __restrict__ O1, unsigned short* __restrict__ O2,
    float* __restrict__ Of, int M, int N, int K)
{
  constexpr int ASZ = 64 * 64;
  constexpr int BSZ = 128 * 64;

  extern __shared__ unsigned short lds[];
  const int tid = threadIdx.x;
  const int lane = tid & 63, w = tid >> 6;
  const int g = lane >> 4, q = lane & 15;
  const long bm = (long)blockIdx.y * 64, bn = (long)blockIdx.x * 128;
  const int NK = K >> 6;

  const int srl = lane >> 3;
  const int scE = ((lane & 7) ^ srl) * 8;
  const int c0 = (g ^ (q & 7)) * 8;
  const int c1 = c0 ^ 32;
  const int aB = q * 64;
  const int bB = (w * 32 + q) * 64;

  f32x4 acc[4][2] = {};
  short8 a[4][2], b[2][2];

#define STAGE_A(jj) do {                                                      \
    unsigned short* dst_ = lds + (((jj) & 1) ? ASZ : 0);                      \
    _Pragma("unroll")                                                         \
    for (int c_ = 0; c_ < 2; ++c_) {                                          \
      const long row_ = (c_ * 4 + w) * 8 + srl;                               \
      gload_lds16(&A[(bm + row_) * (long)K + (jj) * 64 + scE],                \
                  &dst_[(c_ * 4 + w) * 512]);                                 \
    }                                                                         \
  } while (0)

#define STAGE_B(jj) do {                                                      \
    unsigned short* dst_ = lds + 2 * ASZ + (((jj) & 1) ? BSZ : 0);            \
    _Pragma("unroll")                                                         \
    for (int c_ = 0; c_ < 4; ++c_) {                                          \
      const long row_ = (c_ * 4 + w) * 8 + srl;                               \
      gload_lds16(&B[(bn + row_) * (long)K + (jj) * 64 + scE],                \
                  &dst_[(c_ * 4 + w) * 512]);                                 \
    }                                                                         \
  } while (0)

#define QUAD8(ni)                                                             \
  do {                                                                        \
    __builtin_amdgcn_s_setprio(1);                                            \
    _Pragma("unroll")                                                         \
    for (int mi_ = 0; mi_ < 4; ++mi_) {                                       \
      acc[mi_][ni] = __builtin_amdgcn_mfma_f32_16x16x32_bf16(                 \
          a[mi_][0], b[ni][0], acc[mi_][ni], 0, 0, 0);                        \
      acc[mi_][ni] = __builtin_amdgcn_mfma_f32_16x16x32_bf16(                 \
          a[mi_][1], b[ni][1], acc[mi_][ni], 0, 0, 0);                        \
    }                                                                         \
    __builtin_amdgcn_s_setprio(0);                                            \
  } while (0)

  STAGE_A(0); STAGE_B(0);
  STAGE_A(1); STAGE_B(1);
  VM6();
  BAR();

  for (int j = 0; j < NK; ++j) {
    unsigned short* At = lds + ((j & 1) ? ASZ : 0);
    unsigned short* Bt = lds + 2 * ASZ + ((j & 1) ? BSZ : 0);

#pragma unroll
    for (int mi = 0; mi < 4; ++mi) {
      a[mi][0] = *(const short8*)&At[aB + mi * 1024 + c0];
      a[mi][1] = *(const short8*)&At[aB + mi * 1024 + c1];
    }
#pragma unroll
    for (int ni = 0; ni < 2; ++ni) {
      b[ni][0] = *(const short8*)&Bt[bB + ni * 1024 + c0];
      b[ni][1] = *(const short8*)&Bt[bB + ni * 1024 + c1];
    }
    QUAD8(0);
    LGKM0();
    BAR();                                  // (a)
    if (j + 2 < NK) { STAGE_A(j + 2); STAGE_B(j + 2); }
    QUAD8(1);
    if (j < NK - 2) { VM6(); } else { VM0(); }
    BAR();                                  // (b)
  }

#pragma unroll
  for (int ni = 0; ni < 2; ++ni) {
    const int col = (int)bn + w * 32 + ni * 16 + q;
    float bv;
    if (MODE == 4) {
      const int which = col >> 11, c = col & 2047;
      const float* bp = which == 0 ? b0 : (which == 1 ? b1 : b2);
      bv = bp[c];
    } else {
      bv = b0[col];
    }
#pragma unroll
    for (int mi = 0; mi < 4; ++mi)
#pragma unroll
      for (int r = 0; r < 4; ++r) {
        const long row = bm + mi * 16 + 4 * g + r;
        const float v = acc[mi][ni][r] + bv;
        if (MODE == 4) {
          const int which = col >> 11, c = col & 2047, head = c >> 7, d = c & 127;
          if (which == 0)      O0[((long)head * SEQ + row) * HD + d] = f2bu(v * QSCALE_L2E);
          else if (which == 1) O1[((long)head * SEQ + row) * HD + d] = f2bu(v);
          else                 O2[((long)head * HD + d) * SEQ + row] = f2bu(v);
        } else {
          Of[row * (long)N + col] = v;
        }
      }
  }
#undef STAGE_A
#undef STAGE_B
#undef QUAD8
}

// ---------------- flash attention v12: gload_lds staging ---------------------
// R24: bank-audit found the real 4.19M conflicts: Kt rows (256B) and Vt rows
// (128B) are multiples of the 128B bank cycle, so every ds_write_b128 staging
// instruction (4 rows x 16 lanes K / 8 rows x 8 lanes V) was 8-WAY conflicted.
// Fix = gemm97's proven pattern: global_load_lds with LINEAR LDS dest
// (wave-uniform base + lane*16 -> HW-native conflict-free) and the XOR
// swizzle folded into the per-lane GLOBAL source address, so the read-side
// layout is bit-identical to the R19-proven one:
//   K lane l, call c: row w*16+c*4+(l>>4), colE ((l&15)^((c&1)*4+(l>>4)))*8
//   V lane l, call c: row w*32+c*8+(l>>3), colE ((l&7)^((l>>3)&7))*8
// Double-buffered (72KB dynamic LDS, 2 blocks/CU), counted vmcnt(8) so the
// next tile's 8 loads stay in flight across barriers. Compute body = R19's
// proven Pt version (R23's shfl exchange reverted: measured -1us).
#define KVB 64
__global__ __launch_bounds__(256) void flash_attn(
    const unsigned short* __restrict__ Qb,
    const unsigned short* __restrict__ Kb,
    const unsigned short* __restrict__ VTb,
    unsigned short* __restrict__ attnb)      // [SEQ][HID] bf16
{
  // S (elements): Kt0 @0 | Kt1 @8192 | Vt0 @16384 | Vt1 @24576 | Pt @32768
  extern __shared__ unsigned short S[];      // 36864 us = 72KB
  const int tid = threadIdx.x;
  const int l = tid & 63, w = tid >> 6;
  const int g = l >> 4, q = l & 15;
  const int bid = blockIdx.x;
  const int jj = bid >> 3;
  const int h = ((bid & 7) << 1) | (jj >> 5);   // 2 heads per XCD (R19-proven)
  const int qb = jj & 31;
  const int qrow0 = qb * 64 + w * 16;

  unsigned short* Pw = S + 32768 + w * 1024;

  short8 qf[4];
#pragma unroll
  for (int dc = 0; dc < 4; ++dc)
    qf[dc] = *(const short8*)&Qb[((long)h * SEQ + qrow0 + q) * HD + dc * 32 + g * 8];

  f32x4 oacc[8] = {};
  float lsum[4] = {0.f, 0.f, 0.f, 0.f};

  const unsigned short* Kg = Kb + (long)h * SEQ * HD;
  const unsigned short* Vg = VTb + (long)h * HD * SEQ;

  // pre-swizzled source column offsets (elements)
  const int kce = ((l & 15) ^ (l >> 4)) * 8;        // K, even calls
  const int kco = kce ^ 32;                         // K, odd calls (XOR 4 blks)
  const int vce = ((l & 7) ^ ((l >> 3) & 7)) * 8;   // V, all calls
  // per-lane row components
  const int krl = l >> 4;                           // K row within 4-row call
  const int vrl = l >> 3;                           // V row within 8-row call

  // wave-uniform LDS bases (HW appends lane*16)
  unsigned short* KdB = S + w * 2048;               // + buf*8192 + c*512
  unsigned short* VdB = S + 16384 + w * 2048;

#define STAGE(kb_, bufsel) do {                                               \
    const unsigned short* Kp_ = Kg + (long)((kb_) + w * 16 + krl) * HD;       \
    const unsigned short* Vp_ = Vg + (long)(w * 32 + vrl) * SEQ + (kb_) + vce;\
    unsigned short* Kd_ = KdB + (bufsel) * 8192;                              \
    unsigned short* Vd_ = VdB + (bufsel) * 8192;                              \
    gload_lds16(Kp_ + 0 * 4 * HD + kce, Kd_ + 0 * 512);                       \
    gload_lds16(Kp_ + 1 * 4 * HD + kco, Kd_ + 1 * 512);                       \
    gload_lds16(Kp_ + 2 * 4 * HD + kce, Kd_ + 2 * 512);                       \
    gload_lds16(Kp_ + 3 * 4 * HD + kco, Kd_ + 3 * 512);                       \
    gload_lds16(Vp_ + 0 * 8 * SEQ, Vd_ + 0 * 512);                            \
    gload_lds16(Vp_ + 1 * 8 * SEQ, Vd_ + 1 * 512);                            \
    gload_lds16(Vp_ + 2 * 8 * SEQ, Vd_ + 2 * 512);                            \
    gload_lds16(Vp_ + 3 * 8 * SEQ, Vd_ + 3 * 512);                            \
  } while (0)

  STAGE(0, 0);
  STAGE(KVB, 1);
  VM8();                                    // tile0's 8 loads landed
  BAR();

  for (int t = 0; t < 32; ++t) {
    const unsigned short* Kt = S + (t & 1) * 8192;
    const unsigned short* Vt = S + 16384 + (t & 1) * 8192;

    f32x4 sacc[4] = {};
    __builtin_amdgcn_s_setprio(1);
#pragma unroll
    for (int kc = 0; kc < 4; ++kc) {
      const int krow = kc * 16 + q;
      const int sw = (krow & 7) << 4;
#pragma unroll
      for (int dc = 0; dc < 4; ++dc) {
        short8 kf = *(const short8*)&Kt[((krow * 256 + dc * 64 + g * 16) ^ sw) >> 1];
        sacc[kc] = __builtin_amdgcn_mfma_f32_16x16x32_bf16(qf[dc], kf, sacc[kc], 0, 0, 0);
      }
    }
    __builtin_amdgcn_s_setprio(0);

    float p[4][4];
#pragma unroll
    for (int r = 0; r < 4; ++r) {
#pragma unroll
      for (int kc = 0; kc < 4; ++kc) p[kc][r] = exp2fast(sacc[kc][r]);
      lsum[r] += (p[0][r] + p[1][r]) + (p[2][r] + p[3][r]);
    }

#pragma unroll
    for (int r = 0; r < 4; ++r) {
      const int prow = 4 * g + r;
      const int sw = (prow & 7) << 4;
#pragma unroll
      for (int kc = 0; kc < 4; ++kc)
        Pw[((prow * 128 + (kc * 16 + q) * 2) ^ sw) >> 1] = f2bu_fast(p[kc][r]);
    }

    short8 pf[2];
    const int psw = (q & 7) << 4;
#pragma unroll
    for (int ks = 0; ks < 2; ++ks)
      pf[ks] = *(const short8*)&Pw[((q * 128 + ks * 64 + g * 16) ^ psw) >> 1];
    __builtin_amdgcn_s_setprio(1);
#pragma unroll
    for (int dt = 0; dt < 8; ++dt) {
      const int vrow = dt * 16 + q;
#pragma unroll
      for (int ks = 0; ks < 2; ++ks) {
        short8 vf = *(const short8*)&Vt[((vrow * 128 + ks * 64 + g * 16) ^ psw) >> 1];
        oacc[dt] = __builtin_amdgcn_mfma_f32_16x16x32_bf16(pf[ks], vf, oacc[dt], 0, 0, 0);
      }
    }
    __builtin_amdgcn_s_setprio(0);

    BAR();                                  // all waves done reading buf[t&1]
    if (t + 2 < 32) STAGE((t + 2) * KVB, t & 1);
    if (t < 30) { VM8(); } else { VM0(); }  // tile t+1 fully landed
    BAR();
  }

  // sum exp over the 16 q-lanes (KV columns live on q within each 16-lane grp)
#pragma unroll
  for (int off = 1; off < 16; off <<= 1)
#pragma unroll
    for (int r = 0; r < 4; ++r) lsum[r] += __shfl_xor(lsum[r], off);

  const float rl0 = 1.f / lsum[0], rl1 = 1.f / lsum[1];
  const float rl2 = 1.f / lsum[2], rl3 = 1.f / lsum[3];
#pragma unroll
  for (int dt = 0; dt < 8; ++dt) {
    const long colb = (long)h * HD + dt * 16 + q;
    attnb[(long)(qrow0 + 4 * g + 0) * HID + colb] = f2bu(oacc[dt][0] * rl0);
    attnb[(long)(qrow0 + 4 * g + 1) * HID + colb] = f2bu(oacc[dt][1] * rl1);
    attnb[(long)(qrow0 + 4 * g + 2) * HID + colb] = f2bu(oacc[dt][2] * rl2);
    attnb[(long)(qrow0 + 4 * g + 3) * HID + colb] = f2bu(oacc[dt][3] * rl3);
  }
#undef STAGE
}

extern "C" void kernel_launch(void* const* d_in, const int* in_sizes, int n_in,
                              void* d_out, int out_size, void* d_ws, size_t ws_size,
                              hipStream_t stream)
{
  const float* x  = (const float*)d_in[0];
  const float* wq = (const float*)d_in[1];
  const float* bq = (const float*)d_in[2];
  const float* wk = (const float*)d_in[3];
  const float* bk = (const float*)d_in[4];
  const float* wv = (const float*)d_in[5];
  const float* bv = (const float*)d_in[6];
  const float* wo = (const float*)d_in[7];
  const float* bo = (const float*)d_in[8];

  const long NEL = (long)HID * HID;
  unsigned short* Xb   = (unsigned short*)d_ws;
  unsigned short* Wqkv = Xb + NEL;
  unsigned short* Wob  = Wqkv + 3 * NEL;
  unsigned short* Qbuf = Wob + NEL;
  unsigned short* Kbuf = Qbuf + NEL;
  unsigned short* VTb  = Kbuf + NEL;
  unsigned short* Attn = VTb + NEL;

  // one-time opt-in for 72KB dynamic LDS (host-side, graph-capture safe;
  // mechanism verified in R22)
  static bool attrDone = false;
  if (!attrDone) {
    hipFuncSetAttribute(reinterpret_cast<const void*>(flash_attn),
                        hipFuncAttributeMaxDynamicSharedMemorySize, 73728);
    attrDone = true;
  }

  cvt_kernel<<<dim3(512, 5), 256, 0, stream>>>(
      x, wq, wk, wv, wo, Xb, Wqkv, Wqkv + NEL, Wqkv + 2 * NEL, Wob, (int)NEL);

  gemm97<4><<<dim3(48, 16), 256, 32768, stream>>>(
      Xb, Wqkv, bq, bk, bv, Qbuf, Kbuf, VTb, nullptr, SEQ, 3 * HID, HID);

  flash_attn<<<dim3(512), 256, 73728, stream>>>(Qbuf, Kbuf, VTb, Attn);

  gemm128<3><<<dim3(16, 32), 256, 49152, stream>>>(
      Attn, Wob, bo, nullptr, nullptr, nullptr, nullptr, nullptr,
      (float*)d_out, SEQ, HID, HID);
}

// Round 12
// 161.277 us; speedup vs baseline: 1.0240x; 1.0169x over previous
//
#include <hip/hip_runtime.h>
#include <hip/hip_bf16.h>
#include <stdint.h>

#define SEQ 2048
#define HID 2048
#define NH 16
#define HD 128
// 1/sqrt(128) * log2(e): softmax runs in exp2 domain
#define QSCALE_L2E 0.1275304429019769f

typedef __attribute__((ext_vector_type(4))) float f32x4;
typedef __attribute__((ext_vector_type(8))) short short8;
typedef __attribute__((ext_vector_type(4))) float f4;
typedef __attribute__((ext_vector_type(4))) unsigned short us4;

__device__ __forceinline__ unsigned short f2bu(float f) {
  union { float f; unsigned int u; } c; c.f = f;
  unsigned int u = c.u + 0x7fffu + ((c.u >> 16) & 1u);  // RNE, finite inputs
  return (unsigned short)(u >> 16);
}

__device__ __forceinline__ unsigned short f2bu_fast(float f) {
  union { float f; unsigned int u; } c; c.f = f;
  return (unsigned short)((c.u + 0x8000u) >> 16);
}

__device__ __forceinline__ float b2f(unsigned short u) {
  union { unsigned int u; float f; } c; c.u = ((unsigned int)u) << 16; return c.f;
}

__device__ __forceinline__ float exp2fast(float x) {
  float r; asm("v_exp_f32 %0, %1" : "=v"(r) : "v"(x)); return r;
}

__device__ __forceinline__ void gload_lds16(const void* g, void* l) {
  __builtin_amdgcn_global_load_lds((const __attribute__((address_space(1))) void*)g,
                                   (__attribute__((address_space(3))) void*)l, 16, 0, 0);
}

#define BAR() __builtin_amdgcn_s_barrier()
#define LGKM0() do { asm volatile("s_waitcnt lgkmcnt(0)" ::: "memory"); __builtin_amdgcn_sched_barrier(0); } while (0)
#define VM6()   do { asm volatile("s_waitcnt vmcnt(6)"   ::: "memory"); __builtin_amdgcn_sched_barrier(0); } while (0)
#define VM4()   do { asm volatile("s_waitcnt vmcnt(4)"   ::: "memory"); __builtin_amdgcn_sched_barrier(0); } while (0)
#define VM0()   do { asm volatile("s_waitcnt vmcnt(0)"   ::: "memory"); __builtin_amdgcn_sched_barrier(0); } while (0)

// ---------------- fp32 -> bf16 convert, 5 equal-size arrays (32B/thread) ----
__global__ __launch_bounds__(256) void cvt_kernel(
    const float* __restrict__ s0, const float* __restrict__ s1,
    const float* __restrict__ s2, const float* __restrict__ s3,
    const float* __restrict__ s4,
    unsigned short* __restrict__ d0, unsigned short* __restrict__ d1,
    unsigned short* __restrict__ d2, unsigned short* __restrict__ d3,
    unsigned short* __restrict__ d4, int n)
{
  const float* s; unsigned short* d;
  switch (blockIdx.y) {
    case 0: s = s0; d = d0; break;
    case 1: s = s1; d = d1; break;
    case 2: s = s2; d = d2; break;
    case 3: s = s3; d = d3; break;
    default: s = s4; d = d4; break;
  }
  const int stride = gridDim.x * blockDim.x;
  for (int i = blockIdx.x * blockDim.x + threadIdx.x; i * 8 < n; i += stride) {
    f4 v0 = *(const f4*)&s[i * 8];
    f4 v1 = *(const f4*)&s[i * 8 + 4];
    short8 o;
    o[0] = (short)f2bu(v0[0]); o[1] = (short)f2bu(v0[1]);
    o[2] = (short)f2bu(v0[2]); o[3] = (short)f2bu(v0[3]);
    o[4] = (short)f2bu(v1[0]); o[5] = (short)f2bu(v1[1]);
    o[6] = (short)f2bu(v1[2]); o[7] = (short)f2bu(v1[3]);
    *(short8*)&d[i * 8] = o;
  }
}

// ---------------- 128x128 bf16 GEMM, m97-style single-buffer ----------------
// R18-verified WIN: BM=BN=128, BK=64, 4 waves (2Mx2N), per-wave 64x64.
// SINGLE 32KB LDS buffer + launch_bounds(256,3) -> 3 blocks/CU (m114
// cross-block MFMA/staging overlap covers the per-tile drain).
template<int MODE>
__global__ __launch_bounds__(256, 3) void gemm97(
    const unsigned short* __restrict__ A,
    const unsigned short* __restrict__ B,
    const float* __restrict__ b0, const float* __restrict__ b1, const float* __restrict__ b2,
    unsigned short* __restrict__ O0, unsigned short* __restrict__ O1, unsigned short* __restrict__ O2,
    float* __restrict__ Of, int M, int N, int K)
{
  extern __shared__ unsigned short lds[];  // A[128*64] @0, B[128*64] @8192 el
  const int tid = threadIdx.x;
  const int lane = tid & 63, w = tid >> 6;
  const int g = lane >> 4, q = lane & 15;
  const int wgM = w >> 1, wgN = w & 1;     // 2M x 2N wave grid
  const long bm = (long)blockIdx.y * 128, bn = (long)blockIdx.x * 128;
  const int NK = K >> 6;

  const int srl = lane >> 3;
  const int scE = ((lane & 7) ^ srl) * 8;
  const int c0 = (g ^ (q & 7)) * 8;
  const int c1 = c0 ^ 32;
  const int aB = (wgM * 64 + q) * 64;
  const int bB = (wgN * 64 + q) * 64;

  f32x4 acc[4][4] = {};
  short8 a[4][2], b[4][2];

#define STAGE(gp, gbase, jj, ldsOff) do {                                     \
    _Pragma("unroll")                                                         \
    for (int c_ = 0; c_ < 4; ++c_) {                                          \
      const long row_ = (c_ * 4 + w) * 8 + srl;                               \
      gload_lds16(&(gp)[((gbase) + row_) * (long)K + (jj) * 64 + scE],        \
                  &lds[(ldsOff) + (c_ * 4 + w) * 512]);                       \
    }                                                                         \
  } while (0)

#define QUADD(n0, n1)                                                         \
  do {                                                                        \
    __builtin_amdgcn_s_setprio(1);                                            \
    _Pragma("unroll")                                                         \
    for (int mi_ = 0; mi_ < 4; ++mi_) {                                       \
      acc[mi_][n0] = __builtin_amdgcn_mfma_f32_16x16x32_bf16(                 \
          a[mi_][0], b[n0][0], acc[mi_][n0], 0, 0, 0);                        \
      acc[mi_][n0] = __builtin_amdgcn_mfma_f32_16x16x32_bf16(                 \
          a[mi_][1], b[n0][1], acc[mi_][n0], 0, 0, 0);                        \
      acc[mi_][n1] = __builtin_amdgcn_mfma_f32_16x16x32_bf16(                 \
          a[mi_][0], b[n1][0], acc[mi_][n1], 0, 0, 0);                        \
      acc[mi_][n1] = __builtin_amdgcn_mfma_f32_16x16x32_bf16(                 \
          a[mi_][1], b[n1][1], acc[mi_][n1], 0, 0, 0);                        \
    }                                                                         \
    __builtin_amdgcn_s_setprio(0);                                            \
  } while (0)

  for (int j = 0; j < NK; ++j) {
    STAGE(A, bm, j, 0);
    STAGE(B, bn, j, 8192);
    VM0();
    BAR();
#pragma unroll
    for (int mi = 0; mi < 4; ++mi) {
      a[mi][0] = *(const short8*)&lds[aB + mi * 1024 + c0];
      a[mi][1] = *(const short8*)&lds[aB + mi * 1024 + c1];
    }
#pragma unroll
    for (int ni = 0; ni < 4; ++ni) {
      b[ni][0] = *(const short8*)&lds[8192 + bB + ni * 1024 + c0];
      b[ni][1] = *(const short8*)&lds[8192 + bB + ni * 1024 + c1];
    }
    QUADD(0, 1);
    QUADD(2, 3);
    BAR();
  }

#pragma unroll
  for (int ni = 0; ni < 4; ++ni) {
    const int col = (int)bn + wgN * 64 + ni * 16 + q;
    float bv;
    if (MODE == 4) {
      const int which = col >> 11, c = col & 2047;
      const float* bp = which == 0 ? b0 : (which == 1 ? b1 : b2);
      bv = bp[c];
    } else {
      bv = b0[col];
    }
#pragma unroll
    for (int mi = 0; mi < 4; ++mi)
#pragma unroll
      for (int r = 0; r < 4; ++r) {
        const long row = bm + wgM * 64 + mi * 16 + 4 * g + r;
        const float v = acc[mi][ni][r] + bv;
        if (MODE == 4) {
          const int which = col >> 11, c = col & 2047, head = c >> 7, d = c & 127;
          if (which == 0)      O0[((long)head * SEQ + row) * HD + d] = f2bu(v * QSCALE_L2E);
          else if (which == 1) O1[((long)head * SEQ + row) * HD + d] = f2bu(v);
          else                 O2[((long)head * HD + d) * SEQ + row] = f2bu(v);
        } else {
          Of[row * (long)N + col] = v;
        }
      }
  }
#undef STAGE
#undef QUADD
}

// ---------------- 64x128 bf16 GEMM  C = A[M,K] * B[N,K]^T + bias ------------
// Kept for out-projection (grid 16x32 = 512 blocks).
template<int MODE>
__global__ __launch_bounds__(256, 2) void gemm128(
    const unsigned short* __restrict__ A,
    const unsigned short* __restrict__ B,
    const float* __restrict__ b0, const float* __restrict__ b1, const float* __restrict__ b2,
    unsigned short* __restrict__ O0, unsigned short* __restrict__ O1, unsigned short* __restrict__ O2,
    float* __restrict__ Of, int M, int N, int K)
{
  constexpr int ASZ = 64 * 64;
  constexpr int BSZ = 128 * 64;

  extern __shared__ unsigned short lds[];
  const int tid = threadIdx.x;
  const int lane = tid & 63, w = tid >> 6;
  const int g = lane >> 4, q = lane & 15;
  const long bm = (long)blockIdx.y * 64, bn = (long)blockIdx.x * 128;
  const int NK = K >> 6;

  const int srl = lane >> 3;
  const int scE = ((lane & 7) ^ srl) * 8;
  const int c0 = (g ^ (q & 7)) * 8;
  const int c1 = c0 ^ 32;
  const int aB = q * 64;
  const int bB = (w * 32 + q) * 64;

  f32x4 acc[4][2] = {};
  short8 a[4][2], b[2][2];

#define STAGE_A(jj) do {                                                      \
    unsigned short* dst_ = lds + (((jj) & 1) ? ASZ : 0);                      \
    _Pragma("unroll")                                                         \
    for (int c_ = 0; c_ < 2; ++c_) {                                          \
      const long row_ = (c_ * 4 + w) * 8 + srl;                               \
      gload_lds16(&A[(bm + row_) * (long)K + (jj) * 64 + scE],                \
                  &dst_[(c_ * 4 + w) * 512]);                                 \
    }                                                                         \
  } while (0)

#define STAGE_B(jj) do {                                                      \
    unsigned short* dst_ = lds + 2 * ASZ + (((jj) & 1) ? BSZ : 0);            \
    _Pragma("unroll")                                                         \
    for (int c_ = 0; c_ < 4; ++c_) {                                          \
      const long row_ = (c_ * 4 + w) * 8 + srl;                               \
      gload_lds16(&B[(bn + row_) * (long)K + (jj) * 64 + scE],                \
                  &dst_[(c_ * 4 + w) * 512]);                                 \
    }                                                                         \
  } while (0)

#define QUAD8(ni)                                                             \
  do {                                                                        \
    __builtin_amdgcn_s_setprio(1);                                            \
    _Pragma("unroll")                                                         \
    for (int mi_ = 0; mi_ < 4; ++mi_) {                                       \
      acc[mi_][ni] = __builtin_amdgcn_mfma_f32_16x16x32_bf16(                 \
          a[mi_][0], b[ni][0], acc[mi_][ni], 0, 0, 0);                        \
      acc[mi_][ni] = __builtin_amdgcn_mfma_f32_16x16x32_bf16(                 \
          a[mi_][1], b[ni][1], acc[mi_][ni], 0, 0, 0);                        \
    }                                                                         \
    __builtin_amdgcn_s_setprio(0);                                            \
  } while (0)

  STAGE_A(0); STAGE_B(0);
  STAGE_A(1); STAGE_B(1);
  VM6();
  BAR();

  for (int j = 0; j < NK; ++j) {
    unsigned short* At = lds + ((j & 1) ? ASZ : 0);
    unsigned short* Bt = lds + 2 * ASZ + ((j & 1) ? BSZ : 0);

#pragma unroll
    for (int mi = 0; mi < 4; ++mi) {
      a[mi][0] = *(const short8*)&At[aB + mi * 1024 + c0];
      a[mi][1] = *(const short8*)&At[aB + mi * 1024 + c1];
    }
#pragma unroll
    for (int ni = 0; ni < 2; ++ni) {
      b[ni][0] = *(const short8*)&Bt[bB + ni * 1024 + c0];
      b[ni][1] = *(const short8*)&Bt[bB + ni * 1024 + c1];
    }
    QUAD8(0);
    LGKM0();
    BAR();                                  // (a)
    if (j + 2 < NK) { STAGE_A(j + 2); STAGE_B(j + 2); }
    QUAD8(1);
    if (j < NK - 2) { VM6(); } else { VM0(); }
    BAR();                                  // (b)
  }

#pragma unroll
  for (int ni = 0; ni < 2; ++ni) {
    const int col = (int)bn + w * 32 + ni * 16 + q;
    float bv;
    if (MODE == 4) {
      const int which = col >> 11, c = col & 2047;
      const float* bp = which == 0 ? b0 : (which == 1 ? b1 : b2);
      bv = bp[c];
    } else {
      bv = b0[col];
    }
#pragma unroll
    for (int mi = 0; mi < 4; ++mi)
#pragma unroll
      for (int r = 0; r < 4; ++r) {
        const long row = bm + mi * 16 + 4 * g + r;
        const float v = acc[mi][ni][r] + bv;
        if (MODE == 4) {
          const int which = col >> 11, c = col & 2047, head = c >> 7, d = c & 127;
          if (which == 0)      O0[((long)head * SEQ + row) * HD + d] = f2bu(v * QSCALE_L2E);
          else if (which == 1) O1[((long)head * SEQ + row) * HD + d] = f2bu(v);
          else                 O2[((long)head * HD + d) * SEQ + row] = f2bu(v);
        } else {
          Of[row * (long)N + col] = v;
        }
      }
  }
#undef STAGE_A
#undef STAGE_B
#undef QUAD8
}

// ---------------- flash attention v15: QK-ahead software pipeline -----------
// R26: R25's 32x32 restructure failed refcheck (bug unlocatable) -> dropped.
// Base = R24 (PASSED): gload_lds staging, K/V dbuf, Pt path, XCD decode.
// Change: T15-style pipeline. Per phase t:
//   STAGE_K(t+2)->Kbuf[t&1]   (slot freed: QK(t) consumed last phase + BAR)
//   QK(t+1) MFMA chain        (reads Kbuf[(t+1)&1], accum into saccNXT)
//   exp/pack/Pt/pf of tile t  (VALU -- runs under the QK MFMAs, sep. pipe)
//   PV(t) from Vbuf[t&1]
//   BAR ; STAGE_V(t+2)->Vbuf[t&1] ; vmcnt(4) ; BAR
// vmcnt(4) drains {V(t+1), K(t+2)} (each had >=1 full phase in flight),
// leaves V(t+2) outstanding. Tail: t==30,31 -> vmcnt(0). Two named sacc
// sets, loop unrolled x2 (no runtime-indexed acc). Math identical to R24.
#define KVB 64
__global__ __launch_bounds__(256) void flash_attn(
    const unsigned short* __restrict__ Qb,
    const unsigned short* __restrict__ Kb,
    const unsigned short* __restrict__ VTb,
    unsigned short* __restrict__ attnb)      // [SEQ][HID] bf16
{
  // S (elements): Kt0 @0 | Kt1 @8192 | Vt0 @16384 | Vt1 @24576 | Pt @32768
  extern __shared__ unsigned short S[];      // 36864 us = 72KB
  const int tid = threadIdx.x;
  const int l = tid & 63, w = tid >> 6;
  const int g = l >> 4, q = l & 15;
  const int bid = blockIdx.x;
  const int jj = bid >> 3;
  const int h = ((bid & 7) << 1) | (jj >> 5);   // 2 heads per XCD (R19-proven)
  const int qb = jj & 31;
  const int qrow0 = qb * 64 + w * 16;

  unsigned short* Pw = S + 32768 + w * 1024;

  short8 qf[4];
#pragma unroll
  for (int dc = 0; dc < 4; ++dc)
    qf[dc] = *(const short8*)&Qb[((long)h * SEQ + qrow0 + q) * HD + dc * 32 + g * 8];

  f32x4 oacc[8] = {};
  f32x4 saccA[4], saccB[4];
  const f32x4 zero4 = {};
  float lsum[4] = {0.f, 0.f, 0.f, 0.f};

  const unsigned short* Kg = Kb + (long)h * SEQ * HD;
  const unsigned short* Vg = VTb + (long)h * HD * SEQ;

  // R24-proven staging geometry (pre-swizzled global source, linear LDS dest)
  const int kce = ((l & 15) ^ (l >> 4)) * 8;        // K, even calls
  const int kco = kce ^ 32;                         // K, odd calls
  const int vce = ((l & 7) ^ ((l >> 3) & 7)) * 8;   // V, all calls
  const int krl = l >> 4;
  const int vrl = l >> 3;
  unsigned short* KdB = S + w * 2048;               // + buf*8192 + c*512
  unsigned short* VdB = S + 16384 + w * 2048;

#define STAGE_K(kb_, bufsel) do {                                             \
    const unsigned short* Kp_ = Kg + (long)((kb_) + w * 16 + krl) * HD;       \
    unsigned short* Kd_ = KdB + (bufsel) * 8192;                              \
    gload_lds16(Kp_ + 0 * 4 * HD + kce, Kd_ + 0 * 512);                       \
    gload_lds16(Kp_ + 1 * 4 * HD + kco, Kd_ + 1 * 512);                       \
    gload_lds16(Kp_ + 2 * 4 * HD + kce, Kd_ + 2 * 512);                       \
    gload_lds16(Kp_ + 3 * 4 * HD + kco, Kd_ + 3 * 512);                       \
  } while (0)

#define STAGE_V(kb_, bufsel) do {                                             \
    const unsigned short* Vp_ = Vg + (long)(w * 32 + vrl) * SEQ + (kb_) + vce;\
    unsigned short* Vd_ = VdB + (bufsel) * 8192;                              \
    gload_lds16(Vp_ + 0 * 8 * SEQ, Vd_ + 0 * 512);                            \
    gload_lds16(Vp_ + 1 * 8 * SEQ, Vd_ + 1 * 512);                            \
    gload_lds16(Vp_ + 2 * 8 * SEQ, Vd_ + 2 * 512);                            \
    gload_lds16(Vp_ + 3 * 8 * SEQ, Vd_ + 3 * 512);                            \
  } while (0)

#define QKT(T1, SN) do {                                                      \
    const unsigned short* Kt_ = S + ((T1) & 1) * 8192;                        \
    __builtin_amdgcn_s_setprio(1);                                            \
    _Pragma("unroll")                                                         \
    for (int kc = 0; kc < 4; ++kc) {                                          \
      const int krow_ = kc * 16 + q;                                          \
      const int sw_ = (krow_ & 7) << 4;                                       \
      _Pragma("unroll")                                                       \
      for (int dc = 0; dc < 4; ++dc) {                                        \
        short8 kf_ = *(const short8*)&Kt_[((krow_ * 256 + dc * 64 + g * 16) ^ sw_) >> 1]; \
        SN[kc] = __builtin_amdgcn_mfma_f32_16x16x32_bf16(qf[dc], kf_, SN[kc], 0, 0, 0);   \
      }                                                                       \
    }                                                                         \
    __builtin_amdgcn_s_setprio(0);                                            \
  } while (0)

#define FINISH_PV(T, SC) do {                                                 \
    float p_[4][4];                                                           \
    _Pragma("unroll")                                                         \
    for (int r = 0; r < 4; ++r) {                                             \
      _Pragma("unroll")                                                       \
      for (int kc = 0; kc < 4; ++kc) p_[kc][r] = exp2fast(SC[kc][r]);         \
      lsum[r] += (p_[0][r] + p_[1][r]) + (p_[2][r] + p_[3][r]);               \
    }                                                                         \
    _Pragma("unroll")                                                         \
    for (int r = 0; r < 4; ++r) {                                             \
      const int prow_ = 4 * g + r;                                            \
      const int sw_ = (prow_ & 7) << 4;                                       \
      _Pragma("unroll")                                                       \
      for (int kc = 0; kc < 4; ++kc)                                          \
        Pw[((prow_ * 128 + (kc * 16 + q) * 2) ^ sw_) >> 1] = f2bu_fast(p_[kc][r]); \
    }                                                                         \
    short8 pf_[2];                                                            \
    const int psw_ = (q & 7) << 4;                                            \
    _Pragma("unroll")                                                         \
    for (int ks = 0; ks < 2; ++ks)                                            \
      pf_[ks] = *(const short8*)&Pw[((q * 128 + ks * 64 + g * 16) ^ psw_) >> 1]; \
    const unsigned short* Vt_ = S + 16384 + ((T) & 1) * 8192;                 \
    __builtin_amdgcn_s_setprio(1);                                            \
    _Pragma("unroll")                                                         \
    for (int dt = 0; dt < 8; ++dt) {                                          \
      const int vrow_ = dt * 16 + q;                                          \
      _Pragma("unroll")                                                       \
      for (int ks = 0; ks < 2; ++ks) {                                        \
        short8 vf_ = *(const short8*)&Vt_[((vrow_ * 128 + ks * 64 + g * 16) ^ psw_) >> 1]; \
        oacc[dt] = __builtin_amdgcn_mfma_f32_16x16x32_bf16(pf_[ks], vf_, oacc[dt], 0, 0, 0); \
      }                                                                       \
    }                                                                         \
    __builtin_amdgcn_s_setprio(0);                                            \
  } while (0)

#define PHASE(T, SC, SN) do {                                                 \
    if ((T) + 2 < 32) STAGE_K(((T) + 2) * KVB, (T) & 1);                      \
    if ((T) + 1 < 32) {                                                       \
      _Pragma("unroll")                                                       \
      for (int kc = 0; kc < 4; ++kc) SN[kc] = zero4;                          \
      QKT((T) + 1, SN);                                                       \
    }                                                                         \
    FINISH_PV(T, SC);                                                         \
    BAR();                                                                    \
    if ((T) + 2 < 32) STAGE_V(((T) + 2) * KVB, (T) & 1);                      \
    if ((T) <= 29) { VM4(); } else { VM0(); }                                 \
    BAR();                                                                    \
  } while (0)

  // ---- prologue: tiles 0,1 staged; QK(0) computed; barrier so no wave
  // overwrites Kbuf0 (phase 0's STAGE_K(2)) before all waves read it.
  STAGE_K(0, 0); STAGE_V(0, 0);
  STAGE_K(KVB, 1); STAGE_V(KVB, 1);
  VM0();
  BAR();
#pragma unroll
  for (int kc = 0; kc < 4; ++kc) saccA[kc] = zero4;
  QKT(0, saccA);
  BAR();

  for (int t = 0; t < 32; t += 2) {
    PHASE(t, saccA, saccB);
    PHASE(t + 1, saccB, saccA);
  }

  // sum exp over the 16 q-lanes (KV columns live on q within each 16-lane grp)
#pragma unroll
  for (int off = 1; off < 16; off <<= 1)
#pragma unroll
    for (int r = 0; r < 4; ++r) lsum[r] += __shfl_xor(lsum[r], off);

  const float rl0 = 1.f / lsum[0], rl1 = 1.f / lsum[1];
  const float rl2 = 1.f / lsum[2], rl3 = 1.f / lsum[3];
#pragma unroll
  for (int dt = 0; dt < 8; ++dt) {
    const long colb = (long)h * HD + dt * 16 + q;
    attnb[(long)(qrow0 + 4 * g + 0) * HID + colb] = f2bu(oacc[dt][0] * rl0);
    attnb[(long)(qrow0 + 4 * g + 1) * HID + colb] = f2bu(oacc[dt][1] * rl1);
    attnb[(long)(qrow0 + 4 * g + 2) * HID + colb] = f2bu(oacc[dt][2] * rl2);
    attnb[(long)(qrow0 + 4 * g + 3) * HID + colb] = f2bu(oacc[dt][3] * rl3);
  }
#undef STAGE_K
#undef STAGE_V
#undef QKT
#undef FINISH_PV
#undef PHASE
}

extern "C" void kernel_launch(void* const* d_in, const int* in_sizes, int n_in,
                              void* d_out, int out_size, void* d_ws, size_t ws_size,
                              hipStream_t stream)
{
  const float* x  = (const float*)d_in[0];
  const float* wq = (const float*)d_in[1];
  const float* bq = (const float*)d_in[2];
  const float* wk = (const float*)d_in[3];
  const float* bk = (const float*)d_in[4];
  const float* wv = (const float*)d_in[5];
  const float* bv = (const float*)d_in[6];
  const float* wo = (const float*)d_in[7];
  const float* bo = (const float*)d_in[8];

  const long NEL = (long)HID * HID;
  unsigned short* Xb   = (unsigned short*)d_ws;
  unsigned short* Wqkv = Xb + NEL;
  unsigned short* Wob  = Wqkv + 3 * NEL;
  unsigned short* Qbuf = Wob + NEL;
  unsigned short* Kbuf = Qbuf + NEL;
  unsigned short* VTb  = Kbuf + NEL;
  unsigned short* Attn = VTb + NEL;

  // one-time opt-in for 72KB dynamic LDS (host-side, graph-capture safe)
  static bool attrDone = false;
  if (!attrDone) {
    hipFuncSetAttribute(reinterpret_cast<const void*>(flash_attn),
                        hipFuncAttributeMaxDynamicSharedMemorySize, 73728);
    attrDone = true;
  }

  cvt_kernel<<<dim3(512, 5), 256, 0, stream>>>(
      x, wq, wk, wv, wo, Xb, Wqkv, Wqkv + NEL, Wqkv + 2 * NEL, Wob, (int)NEL);

  gemm97<4><<<dim3(48, 16), 256, 32768, stream>>>(
      Xb, Wqkv, bq, bk, bv, Qbuf, Kbuf, VTb, nullptr, SEQ, 3 * HID, HID);

  flash_attn<<<dim3(512), 256, 73728, stream>>>(Qbuf, Kbuf, VTb, Attn);

  gemm128<3><<<dim3(16, 32), 256, 49152, stream>>>(
      Attn, Wob, bo, nullptr, nullptr, nullptr, nullptr, nullptr,
      (float*)d_out, SEQ, HID, HID);
}